// Round 7
// baseline (733.011 us; speedup 1.0000x reference)
//
#include <hip/hip_runtime.h>
#include <math.h>

constexpr int NN = 100000;
constexpr int NE = 1600000;
constexpr int NG = 512;
constexpr int NBKT = (NN + 127) / 128;   // 782 dst-buckets (128 nodes each)
constexpr int BCAP = 3072;               // bucket capacity (mean 2048, sd ~45)

typedef unsigned short bf16_t;
__device__ __forceinline__ bf16_t f2bf(float f) {
    unsigned u = __float_as_uint(f);
    unsigned r = (u + 0x7fffu + ((u >> 16) & 1u)) >> 16;   // round-nearest-even
    return (bf16_t)r;
}
__device__ __forceinline__ float bf2f(bf16_t h) {
    return __uint_as_float(((unsigned)h) << 16);
}
__device__ __forceinline__ float eluf(float x) {
    return x > 0.f ? x : expm1f(x);
}

// dst-bucket histogram, LDS-aggregated
__global__ void k_hist(const int* __restrict__ dst, int* __restrict__ bktCnt) {
    __shared__ int h[NBKT];
    for (int i = threadIdx.x; i < NBKT; i += 256) h[i] = 0;
    __syncthreads();
    int tot = gridDim.x * 256;
    for (int e = blockIdx.x * 256 + threadIdx.x; e < NE; e += tot) {
        int d = __builtin_nontemporal_load(dst + e);
        atomicAdd(&h[d >> 7], 1);
    }
    __syncthreads();
    for (int i = threadIdx.x; i < NBKT; i += 256)
        if (h[i]) atomicAdd(&bktCnt[i], h[i]);
}

// block 0: exclusive scan of bucket counts; block 1: gptr from sorted batch
__global__ void k_small(const int* __restrict__ bktCnt, int* __restrict__ bktBase,
                        int* __restrict__ bktCur, const int* __restrict__ batch,
                        int* __restrict__ gptr, int* __restrict__ rowptr) {
    if (blockIdx.x == 0) {
        __shared__ int sh[1024];
        int tid = threadIdx.x;
        int v = (tid < NBKT) ? bktCnt[tid] : 0;
        sh[tid] = v;
        __syncthreads();
        for (int off = 1; off < 1024; off <<= 1) {
            int t = (tid >= off) ? sh[tid - off] : 0;
            __syncthreads();
            sh[tid] += t;
            __syncthreads();
        }
        if (tid < NBKT) { int ex = sh[tid] - v; bktBase[tid] = ex; bktCur[tid] = ex; }
        if (tid == NBKT - 1) bktBase[NBKT] = sh[tid];   // == NE
        if (tid == 0) rowptr[NN] = NE;
    } else {
        int g = threadIdx.x;
        if (g > NG) return;
        if (g == NG) { gptr[NG] = NN; return; }
        int lo = 0, hi = NN;
        while (lo < hi) {
            int mid = (lo + hi) >> 1;
            if (batch[mid] < g) lo = mid + 1; else hi = mid;
        }
        gptr[g] = lo;
    }
}

// scatter edges into their dst-bucket region; pack src(17b)<<7 | dstLow(7b)
__global__ void k_scatter_bkt(const int* __restrict__ src, const int* __restrict__ dst,
                              int* __restrict__ bktCur, int* __restrict__ ebuf) {
    int e = blockIdx.x * 256 + threadIdx.x;
    if (e >= NE) return;
    int s = __builtin_nontemporal_load(src + e);
    int d = __builtin_nontemporal_load(dst + e);
    int pos = atomicAdd(&bktCur[d >> 7], 1);
    ebuf[pos] = (s << 7) | (d & 127);
}

// per-bucket LDS counting sort -> csr_src (sequential writes), rowptr, dinv
__global__ __launch_bounds__(256) void k_bktsort(const int* __restrict__ bktBase,
                                                 const int* __restrict__ ebuf,
                                                 int* __restrict__ csr,
                                                 int* __restrict__ rowptr,
                                                 float* __restrict__ dinv) {
    __shared__ int sbuf[BCAP];
    __shared__ int cnt[128], scn[128], cur[128];
    int b = blockIdx.x, tid = threadIdx.x;
    int base = bktBase[b];
    int n = min(bktBase[b + 1] - base, BCAP);
    for (int i = tid; i < n; i += 256) sbuf[i] = __builtin_nontemporal_load(ebuf + base + i);
    if (tid < 128) cnt[tid] = 0;
    __syncthreads();
    for (int i = tid; i < n; i += 256) atomicAdd(&cnt[sbuf[i] & 127], 1);
    __syncthreads();
    int v = (tid < 128) ? cnt[tid] : 0;
    if (tid < 128) scn[tid] = v;
    __syncthreads();
    for (int off = 1; off < 128; off <<= 1) {
        int t = (tid < 128 && tid >= off) ? scn[tid - off] : 0;
        __syncthreads();
        if (tid < 128) scn[tid] += t;
        __syncthreads();
    }
    if (tid < 128) {
        int ex = scn[tid] - v;
        cur[tid] = ex;
        int node = b * 128 + tid;
        if (node < NN) {
            rowptr[node] = base + ex;
            dinv[node] = rsqrtf((float)v + 1.0f);
        }
    }
    __syncthreads();
    for (int i = tid; i < n; i += 256) {
        int p = sbuf[i];
        int pos = atomicAdd(&cur[p & 127], 1);
        csr[base + pos] = p >> 7;
    }
}

// LDS-tiled layer-1 GEMM, epilogue y1 = dinv * (x @ W1), bf16
__global__ void k_gemm1(const float* __restrict__ x, const float* __restrict__ W1,
                        const float* __restrict__ dinv, bf16_t* __restrict__ y1) {
    __shared__ float sx[64 * 66];
    __shared__ float sw[66 * 64];
    int tid = threadIdx.x;
    for (int i = tid; i < 66 * 64; i += 256) sw[i] = W1[i];
    int base = blockIdx.x * 64;
    int rows = min(64, NN - base);
    int cnt = rows * 66;
    for (int i = tid; i < cnt; i += 256) sx[i] = x[base * 66 + i];
    __syncthreads();
    int c = tid & 63, rg = tid >> 6;
    float acc[16];
#pragma unroll
    for (int i = 0; i < 16; ++i) acc[i] = 0.f;
    for (int k = 0; k < 66; ++k) {
        float wv = sw[k * 64 + c];
#pragma unroll
        for (int rr = 0; rr < 16; ++rr)
            acc[rr] = fmaf(sx[(rg * 16 + rr) * 66 + k], wv, acc[rr]);
    }
#pragma unroll
    for (int rr = 0; rr < 16; ++rr) {
        int n = base + rg * 16 + rr;
        if (n < NN) y1[n * 64 + c] = f2bf(dinv[n] * acc[rr]);
    }
}

// CSR gather on y = dinv*xw: agg[n] = dinv[n]*(sum y[src] + y[n]).
// 2 nodes per lane-group, masked 8-wide rounds; no per-edge coef at all.
template<int C>
__global__ void k_gather(const int* __restrict__ rowptr, const int* __restrict__ csr,
                         const float* __restrict__ dinv,
                         const bf16_t* __restrict__ y, bf16_t* __restrict__ agg,
                         float* __restrict__ sums, float* __restrict__ sqs) {
    constexpr int NPB = 256 / C;
    int c = threadIdx.x & (C - 1);
    int grp = threadIdx.x / C;
    float s_acc = 0.f, sq_acc = 0.f;
    int stride = gridDim.x * NPB * 2;
    for (int n0 = (blockIdx.x * NPB + grp) * 2; n0 < NN; n0 += stride) {
        int n1 = n0 + 1;
        bool has1 = (n1 < NN);
        int b0 = rowptr[n0];
        int e0 = rowptr[n0 + 1];
        int e1 = has1 ? rowptr[n1 + 1] : e0;
        int safe0 = (b0 < NE) ? b0 : 0;
        int safe1 = (e0 < NE) ? e0 : 0;      // row n1 starts at e0 (contiguous)
        float acc0 = 0.f, acc1 = 0.f;
        int j0 = b0, j1 = e0;
        while (j0 < e0 || j1 < e1) {
            int s0[8], s1[8];
#pragma unroll
            for (int k = 0; k < 8; ++k) {
                int i = j0 + k;
                s0[k] = __builtin_nontemporal_load(csr + ((i < e0) ? i : safe0));
            }
#pragma unroll
            for (int k = 0; k < 8; ++k) {
                int i = j1 + k;
                s1[k] = __builtin_nontemporal_load(csr + ((i < e1) ? i : safe1));
            }
            float v0[8], v1[8];
#pragma unroll
            for (int k = 0; k < 8; ++k) v0[k] = bf2f(y[s0[k] * C + c]);
#pragma unroll
            for (int k = 0; k < 8; ++k) v1[k] = bf2f(y[s1[k] * C + c]);
#pragma unroll
            for (int k = 0; k < 8; ++k) acc0 += (j0 + k < e0) ? v0[k] : 0.f;
#pragma unroll
            for (int k = 0; k < 8; ++k) acc1 += (j1 + k < e1) ? v1[k] : 0.f;
            j0 += 8; j1 += 8;
        }
        float a0 = dinv[n0] * (acc0 + bf2f(y[n0 * C + c]));
        agg[n0 * C + c] = f2bf(a0);
        s_acc += a0;
        sq_acc += a0 * a0;
        if (has1) {
            float a1 = dinv[n1] * (acc1 + bf2f(y[n1 * C + c]));
            agg[n1 * C + c] = f2bf(a1);
            s_acc += a1;
            sq_acc += a1 * a1;
        }
    }
    __shared__ float red[256];
    red[threadIdx.x] = s_acc;
    __syncthreads();
    if (threadIdx.x < C) {
        float tot = 0.f;
#pragma unroll
        for (int i = 0; i < NPB; ++i) tot += red[threadIdx.x + i * C];
        unsafeAtomicAdd(&sums[threadIdx.x], tot);
    }
    __syncthreads();
    red[threadIdx.x] = sq_acc;
    __syncthreads();
    if (threadIdx.x < C) {
        float tot = 0.f;
#pragma unroll
        for (int i = 0; i < NPB; ++i) tot += red[threadIdx.x + i * C];
        unsafeAtomicAdd(&sqs[threadIdx.x], tot);
    }
}

// fused: scale/shift from sums/sqs, h1 = elu(bn(agg1)) in LDS, y2 = dinv*(h1@W2)
__global__ void k_bn_gemm2(const bf16_t* __restrict__ agg1, const float* __restrict__ sums,
                           const float* __restrict__ sqs, const float* __restrict__ gamma,
                           const float* __restrict__ beta, const float* __restrict__ W2,
                           const float* __restrict__ dinv, bf16_t* __restrict__ y2) {
    __shared__ float sh[8 * 64];
    __shared__ float sW[64 * 32];
    __shared__ float sscale[64], sshift[64];
    int tid = threadIdx.x;
    if (tid < 64) {
        float mu = sums[tid] * (1.0f / NN);
        float var = sqs[tid] * (1.0f / NN) - mu * mu;
        float sc = gamma[tid] * rsqrtf(var + 1e-5f);
        sscale[tid] = sc;
        sshift[tid] = beta[tid] - mu * sc;
    }
#pragma unroll
    for (int i = tid; i < 64 * 32; i += 256) sW[i] = W2[i];
    __syncthreads();
    int base = blockIdx.x * 8;
#pragma unroll
    for (int i = tid; i < 512; i += 256) {
        int r = i >> 6, cc = i & 63;
        int n = base + r;
        sh[i] = (n < NN) ? eluf(fmaf(bf2f(agg1[n * 64 + cc]), sscale[cc], sshift[cc])) : 0.f;
    }
    __syncthreads();
    int r = tid >> 5, c = tid & 31;
    int n = base + r;
    if (n < NN) {
        float acc = 0.f;
#pragma unroll
        for (int k = 0; k < 64; ++k) acc = fmaf(sh[r * 64 + k], sW[k * 32 + c], acc);
        y2[n * 32 + c] = f2bf(dinv[n] * acc);
    }
}

// fused: BN stats -> scale/shift, segment pool (no atomics), 2-layer MLP head
__global__ void k_poolmlp(const bf16_t* __restrict__ agg2, const float* __restrict__ sums,
                          const float* __restrict__ sqs, const float* __restrict__ gamma,
                          const float* __restrict__ beta, const int* __restrict__ gptr,
                          const float* __restrict__ Wm1, const float* __restrict__ bm1,
                          const float* __restrict__ Wm2, const float* __restrict__ bm2,
                          float* __restrict__ out) {
    __shared__ float sscale[32], sshift[32];
    __shared__ float red[256];
    __shared__ float gr[64];
    __shared__ float h[32];
    int tid = threadIdx.x;
    if (tid < 32) {
        float mu = sums[tid] * (1.0f / NN);
        float var = sqs[tid] * (1.0f / NN) - mu * mu;
        float sc = gamma[tid] * rsqrtf(var + 1e-5f);
        sscale[tid] = sc;
        sshift[tid] = beta[tid] - mu * sc;
    }
    __syncthreads();
    int g = blockIdx.x;
    int c = tid & 31, r = tid >> 5;
    int beg = gptr[g], end = gptr[g + 1];
    float scl = sscale[c], shf = sshift[c];
    float s = 0.f, m = -INFINITY;
    for (int n = beg + r; n < end; n += 8) {
        float v = eluf(fmaf(bf2f(agg2[n * 32 + c]), scl, shf));
        s += v;
        m = fmaxf(m, v);
    }
    red[tid] = s;
    __syncthreads();
    int cnt = end - beg;
    if (r == 0) {
        float stot = 0.f;
#pragma unroll
        for (int i = 0; i < 8; ++i) stot += red[i * 32 + c];
        gr[c] = stot / fmaxf((float)cnt, 1.f);
    }
    __syncthreads();
    red[tid] = m;
    __syncthreads();
    if (r == 0) {
        float mtot = -INFINITY;
#pragma unroll
        for (int i = 0; i < 8; ++i) mtot = fmaxf(mtot, red[i * 32 + c]);
        gr[32 + c] = (cnt > 0) ? mtot : 0.f;
    }
    __syncthreads();
    if (tid < 32) {
        float acc = bm1[tid];
#pragma unroll
        for (int k = 0; k < 64; ++k) acc = fmaf(gr[k], Wm1[k * 32 + tid], acc);
        h[tid] = eluf(acc);
    }
    __syncthreads();
    if (tid < 2) {
        float acc = bm2[tid];
#pragma unroll
        for (int k = 0; k < 32; ++k) acc = fmaf(h[k], Wm2[k * 2 + tid], acc);
        out[g * 2 + tid] = acc;
    }
}

extern "C" void kernel_launch(void* const* d_in, const int* in_sizes, int n_in,
                              void* d_out, int out_size, void* d_ws, size_t ws_size,
                              hipStream_t stream) {
    const float* x    = (const float*)d_in[0];
    const int*   eidx = (const int*)d_in[1];
    const int*   src  = eidx;
    const int*   dst  = eidx + NE;
    const int*   batch = (const int*)d_in[3];
    const float* W1  = (const float*)d_in[4];
    const float* g1  = (const float*)d_in[6];
    const float* be1 = (const float*)d_in[7];
    const float* W2  = (const float*)d_in[8];
    const float* g2  = (const float*)d_in[10];
    const float* be2 = (const float*)d_in[11];
    const float* Wm1 = (const float*)d_in[12];
    const float* bm1 = (const float*)d_in[13];
    const float* Wm2 = (const float*)d_in[14];
    const float* bm2 = (const float*)d_in[15];
    float* out = (float*)d_out;

    // ---- workspace layout ----
    int*    bktCnt  = (int*)d_ws;                 // 800 (782 used) -- zeroed
    float*  S       = (float*)(bktCnt + 800);     // 512 stat floats -- zeroed
    int*    bktBase = (int*)(S + 512);            // 800 (783 used)
    int*    bktCur  = bktBase + 800;              // 800
    int*    gptr    = bktCur + 800;               // 544 (513 used)
    int*    ebuf    = gptr + 544;                 // NE packed {src<<7|dstLow}
    int*    csr     = ebuf + NE;                  // NE src ids
    int*    rowptr  = csr + NE;                   // 100032 (incl [NN])
    float*  dinv    = (float*)(rowptr + 100032);  // 100000
    bf16_t* y1      = (bf16_t*)(dinv + 100000);   // NN*64
    bf16_t* agg1    = y1 + NN * 64;               // NN*64
    bf16_t* y2      = agg1 + NN * 64;             // NN*32
    bf16_t* agg2    = y2 + NN * 32;               // NN*32

    float* sum1 = S;        float* sq1 = S + 64;
    float* sum2 = S + 128;  float* sq2 = S + 160;

    // ---- init: bucket counts + stats in one memset ----
    hipMemsetAsync(bktCnt, 0, (800 + 512) * sizeof(int), stream);

    // ---- CSR build: histogram -> scan(+gptr) -> bucket scatter -> bucket sort ----
    k_hist<<<192, 256, 0, stream>>>(dst, bktCnt);
    k_small<<<2, 1024, 0, stream>>>(bktCnt, bktBase, bktCur, batch, gptr, rowptr);
    k_scatter_bkt<<<(NE + 255) / 256, 256, 0, stream>>>(src, dst, bktCur, ebuf);
    k_bktsort<<<NBKT, 256, 0, stream>>>(bktBase, ebuf, csr, rowptr, dinv);

    // ---- layer 1 (bias dropped: BN shift-invariant; y1 = dinv * xW1) ----
    k_gemm1<<<(NN + 63) / 64, 256, 0, stream>>>(x, W1, dinv, y1);
    k_gather<64><<<2048, 256, 0, stream>>>(rowptr, csr, dinv, y1, agg1, sum1, sq1);

    // ---- layer 2 (BN+ELU+stats fused into GEMM; y2 = dinv * h1W2) ----
    k_bn_gemm2<<<(NN + 7) / 8, 256, 0, stream>>>(agg1, sum1, sq1, g1, be1, W2, dinv, y2);
    k_gather<32><<<2048, 256, 0, stream>>>(rowptr, csr, dinv, y2, agg2, sum2, sq2);

    // ---- pooling + MLP head in one kernel ----
    k_poolmlp<<<NG, 256, 0, stream>>>(agg2, sum2, sq2, g2, be2, gptr,
                                      Wm1, bm1, Wm2, bm2, out);
}

// Round 8
// 400.573 us; speedup vs baseline: 1.8299x; 1.8299x over previous
//
#include <hip/hip_runtime.h>
#include <math.h>

constexpr int NN = 100000;
constexpr int NE = 1600000;
constexpr int NG = 512;
constexpr int NBKT = (NN + 127) / 128;   // 782 dst-buckets (128 nodes each)
constexpr int BCAP = 3072;               // bucket capacity (mean 2046, sd ~45)

typedef unsigned short bf16_t;
__device__ __forceinline__ bf16_t f2bf(float f) {
    unsigned u = __float_as_uint(f);
    unsigned r = (u + 0x7fffu + ((u >> 16) & 1u)) >> 16;   // round-nearest-even
    return (bf16_t)r;
}
__device__ __forceinline__ float bf2f(bf16_t h) {
    return __uint_as_float(((unsigned)h) << 16);
}
__device__ __forceinline__ float eluf(float x) {
    return x > 0.f ? x : expm1f(x);
}

// dst-bucket histogram, LDS-aggregated
__global__ void k_hist(const int* __restrict__ dst, int* __restrict__ bktCnt) {
    __shared__ int h[NBKT];
    for (int i = threadIdx.x; i < NBKT; i += 256) h[i] = 0;
    __syncthreads();
    int tot = gridDim.x * 256;
    for (int e = blockIdx.x * 256 + threadIdx.x; e < NE; e += tot) {
        int d = __builtin_nontemporal_load(dst + e);
        atomicAdd(&h[d >> 7], 1);
    }
    __syncthreads();
    for (int i = threadIdx.x; i < NBKT; i += 256)
        if (h[i]) atomicAdd(&bktCnt[i], h[i]);
}

// block 0: exclusive scan of bucket counts; block 1: gptr from sorted batch
__global__ void k_small(const int* __restrict__ bktCnt, int* __restrict__ bktBase,
                        int* __restrict__ bktCur, const int* __restrict__ batch,
                        int* __restrict__ gptr, int* __restrict__ rowptr) {
    if (blockIdx.x == 0) {
        __shared__ int sh[1024];
        int tid = threadIdx.x;
        int v = (tid < NBKT) ? bktCnt[tid] : 0;
        sh[tid] = v;
        __syncthreads();
        for (int off = 1; off < 1024; off <<= 1) {
            int t = (tid >= off) ? sh[tid - off] : 0;
            __syncthreads();
            sh[tid] += t;
            __syncthreads();
        }
        if (tid < NBKT) { int ex = sh[tid] - v; bktBase[tid] = ex; bktCur[tid] = ex; }
        if (tid == NBKT - 1) bktBase[NBKT] = sh[tid];   // == NE
        if (tid == 0) rowptr[NN] = NE;
    } else {
        int g = threadIdx.x;
        if (g > NG) return;
        if (g == NG) { gptr[NG] = NN; return; }
        int lo = 0, hi = NN;
        while (lo < hi) {
            int mid = (lo + hi) >> 1;
            if (batch[mid] < g) lo = mid + 1; else hi = mid;
        }
        gptr[g] = lo;
    }
}

// LDS-aggregated bucket scatter: per-block LDS histogram, ONE global atomic
// per (block,bucket) range reservation, then scatter at LDS-cursor offsets.
// 100k global atomics total (vs 1.6M before), writes in ~16-entry runs.
__global__ __launch_bounds__(256) void k_scatter_bkt(const int* __restrict__ src,
                                                     const int* __restrict__ dst,
                                                     int* __restrict__ bktCur,
                                                     int* __restrict__ ebuf) {
    __shared__ int cnt[NBKT];
    __shared__ int base[NBKT];
    int tid = threadIdx.x;
    for (int i = tid; i < NBKT; i += 256) cnt[i] = 0;
    __syncthreads();
    int per = (NE + gridDim.x - 1) / gridDim.x;
    int e0 = blockIdx.x * per;
    int e1 = min(e0 + per, NE);
    for (int e = e0 + tid; e < e1; e += 256) {
        int d = __builtin_nontemporal_load(dst + e);
        atomicAdd(&cnt[d >> 7], 1);
    }
    __syncthreads();
    for (int i = tid; i < NBKT; i += 256) {
        int c = cnt[i];
        base[i] = c ? atomicAdd(&bktCur[i], c) : 0;
        cnt[i] = 0;                 // reuse as local cursor
    }
    __syncthreads();
    for (int e = e0 + tid; e < e1; e += 256) {
        int s = __builtin_nontemporal_load(src + e);
        int d = __builtin_nontemporal_load(dst + e);
        int b = d >> 7;
        int off = atomicAdd(&cnt[b], 1);
        ebuf[base[b] + off] = (s << 7) | (d & 127);
    }
}

// per-bucket LDS counting sort -> csr_src (sequential writes), rowptr, dinv
__global__ __launch_bounds__(256) void k_bktsort(const int* __restrict__ bktBase,
                                                 const int* __restrict__ ebuf,
                                                 int* __restrict__ csr,
                                                 int* __restrict__ rowptr,
                                                 float* __restrict__ dinv) {
    __shared__ int sbuf[BCAP];
    __shared__ int cnt[128], scn[128], cur[128];
    int b = blockIdx.x, tid = threadIdx.x;
    int base = bktBase[b];
    int n = min(bktBase[b + 1] - base, BCAP);
    for (int i = tid; i < n; i += 256) sbuf[i] = __builtin_nontemporal_load(ebuf + base + i);
    if (tid < 128) cnt[tid] = 0;
    __syncthreads();
    for (int i = tid; i < n; i += 256) atomicAdd(&cnt[sbuf[i] & 127], 1);
    __syncthreads();
    int v = (tid < 128) ? cnt[tid] : 0;
    if (tid < 128) scn[tid] = v;
    __syncthreads();
    for (int off = 1; off < 128; off <<= 1) {
        int t = (tid < 128 && tid >= off) ? scn[tid - off] : 0;
        __syncthreads();
        if (tid < 128) scn[tid] += t;
        __syncthreads();
    }
    if (tid < 128) {
        int ex = scn[tid] - v;
        cur[tid] = ex;
        int node = b * 128 + tid;
        if (node < NN) {
            rowptr[node] = base + ex;
            dinv[node] = rsqrtf((float)v + 1.0f);
        }
    }
    __syncthreads();
    for (int i = tid; i < n; i += 256) {
        int p = sbuf[i];
        int pos = atomicAdd(&cur[p & 127], 1);
        csr[base + pos] = p >> 7;
    }
}

// LDS-tiled layer-1 GEMM, epilogue y1 = dinv * (x @ W1), bf16
__global__ void k_gemm1(const float* __restrict__ x, const float* __restrict__ W1,
                        const float* __restrict__ dinv, bf16_t* __restrict__ y1) {
    __shared__ float sx[64 * 66];
    __shared__ float sw[66 * 64];
    int tid = threadIdx.x;
    for (int i = tid; i < 66 * 64; i += 256) sw[i] = W1[i];
    int base = blockIdx.x * 64;
    int rows = min(64, NN - base);
    int cnt = rows * 66;
    for (int i = tid; i < cnt; i += 256) sx[i] = x[base * 66 + i];
    __syncthreads();
    int c = tid & 63, rg = tid >> 6;
    float acc[16];
#pragma unroll
    for (int i = 0; i < 16; ++i) acc[i] = 0.f;
    for (int k = 0; k < 66; ++k) {
        float wv = sw[k * 64 + c];
#pragma unroll
        for (int rr = 0; rr < 16; ++rr)
            acc[rr] = fmaf(sx[(rg * 16 + rr) * 66 + k], wv, acc[rr]);
    }
#pragma unroll
    for (int rr = 0; rr < 16; ++rr) {
        int n = base + rg * 16 + rr;
        if (n < NN) y1[n * 64 + c] = f2bf(dinv[n] * acc[rr]);
    }
}

// CSR gather on y = dinv*xw: agg[n] = dinv[n]*(sum y[src] + y[n]).
// 2 nodes per lane-group, masked 8-wide rounds; no per-edge coef at all.
template<int C>
__global__ void k_gather(const int* __restrict__ rowptr, const int* __restrict__ csr,
                         const float* __restrict__ dinv,
                         const bf16_t* __restrict__ y, bf16_t* __restrict__ agg,
                         float* __restrict__ sums, float* __restrict__ sqs) {
    constexpr int NPB = 256 / C;
    int c = threadIdx.x & (C - 1);
    int grp = threadIdx.x / C;
    float s_acc = 0.f, sq_acc = 0.f;
    int stride = gridDim.x * NPB * 2;
    for (int n0 = (blockIdx.x * NPB + grp) * 2; n0 < NN; n0 += stride) {
        int n1 = n0 + 1;
        bool has1 = (n1 < NN);
        int b0 = rowptr[n0];
        int e0 = rowptr[n0 + 1];
        int e1 = has1 ? rowptr[n1 + 1] : e0;
        int safe0 = (b0 < NE) ? b0 : 0;
        int safe1 = (e0 < NE) ? e0 : 0;      // row n1 starts at e0 (contiguous)
        float acc0 = 0.f, acc1 = 0.f;
        int j0 = b0, j1 = e0;
        while (j0 < e0 || j1 < e1) {
            int s0[8], s1[8];
#pragma unroll
            for (int k = 0; k < 8; ++k) {
                int i = j0 + k;
                s0[k] = __builtin_nontemporal_load(csr + ((i < e0) ? i : safe0));
            }
#pragma unroll
            for (int k = 0; k < 8; ++k) {
                int i = j1 + k;
                s1[k] = __builtin_nontemporal_load(csr + ((i < e1) ? i : safe1));
            }
            float v0[8], v1[8];
#pragma unroll
            for (int k = 0; k < 8; ++k) v0[k] = bf2f(y[s0[k] * C + c]);
#pragma unroll
            for (int k = 0; k < 8; ++k) v1[k] = bf2f(y[s1[k] * C + c]);
#pragma unroll
            for (int k = 0; k < 8; ++k) acc0 += (j0 + k < e0) ? v0[k] : 0.f;
#pragma unroll
            for (int k = 0; k < 8; ++k) acc1 += (j1 + k < e1) ? v1[k] : 0.f;
            j0 += 8; j1 += 8;
        }
        float a0 = dinv[n0] * (acc0 + bf2f(y[n0 * C + c]));
        agg[n0 * C + c] = f2bf(a0);
        s_acc += a0;
        sq_acc += a0 * a0;
        if (has1) {
            float a1 = dinv[n1] * (acc1 + bf2f(y[n1 * C + c]));
            agg[n1 * C + c] = f2bf(a1);
            s_acc += a1;
            sq_acc += a1 * a1;
        }
    }
    __shared__ float red[256];
    red[threadIdx.x] = s_acc;
    __syncthreads();
    if (threadIdx.x < C) {
        float tot = 0.f;
#pragma unroll
        for (int i = 0; i < NPB; ++i) tot += red[threadIdx.x + i * C];
        unsafeAtomicAdd(&sums[threadIdx.x], tot);
    }
    __syncthreads();
    red[threadIdx.x] = sq_acc;
    __syncthreads();
    if (threadIdx.x < C) {
        float tot = 0.f;
#pragma unroll
        for (int i = 0; i < NPB; ++i) tot += red[threadIdx.x + i * C];
        unsafeAtomicAdd(&sqs[threadIdx.x], tot);
    }
}

// fused: scale/shift from sums/sqs, h1 = elu(bn(agg1)) in LDS, y2 = dinv*(h1@W2)
__global__ void k_bn_gemm2(const bf16_t* __restrict__ agg1, const float* __restrict__ sums,
                           const float* __restrict__ sqs, const float* __restrict__ gamma,
                           const float* __restrict__ beta, const float* __restrict__ W2,
                           const float* __restrict__ dinv, bf16_t* __restrict__ y2) {
    __shared__ float sh[8 * 64];
    __shared__ float sW[64 * 32];
    __shared__ float sscale[64], sshift[64];
    int tid = threadIdx.x;
    if (tid < 64) {
        float mu = sums[tid] * (1.0f / NN);
        float var = sqs[tid] * (1.0f / NN) - mu * mu;
        float sc = gamma[tid] * rsqrtf(var + 1e-5f);
        sscale[tid] = sc;
        sshift[tid] = beta[tid] - mu * sc;
    }
#pragma unroll
    for (int i = tid; i < 64 * 32; i += 256) sW[i] = W2[i];
    __syncthreads();
    int base = blockIdx.x * 8;
#pragma unroll
    for (int i = tid; i < 512; i += 256) {
        int r = i >> 6, cc = i & 63;
        int n = base + r;
        sh[i] = (n < NN) ? eluf(fmaf(bf2f(agg1[n * 64 + cc]), sscale[cc], sshift[cc])) : 0.f;
    }
    __syncthreads();
    int r = tid >> 5, c = tid & 31;
    int n = base + r;
    if (n < NN) {
        float acc = 0.f;
#pragma unroll
        for (int k = 0; k < 64; ++k) acc = fmaf(sh[r * 64 + k], sW[k * 32 + c], acc);
        y2[n * 32 + c] = f2bf(dinv[n] * acc);
    }
}

// fused: BN stats -> scale/shift, segment pool (no atomics), 2-layer MLP head
__global__ void k_poolmlp(const bf16_t* __restrict__ agg2, const float* __restrict__ sums,
                          const float* __restrict__ sqs, const float* __restrict__ gamma,
                          const float* __restrict__ beta, const int* __restrict__ gptr,
                          const float* __restrict__ Wm1, const float* __restrict__ bm1,
                          const float* __restrict__ Wm2, const float* __restrict__ bm2,
                          float* __restrict__ out) {
    __shared__ float sscale[32], sshift[32];
    __shared__ float red[256];
    __shared__ float gr[64];
    __shared__ float h[32];
    int tid = threadIdx.x;
    if (tid < 32) {
        float mu = sums[tid] * (1.0f / NN);
        float var = sqs[tid] * (1.0f / NN) - mu * mu;
        float sc = gamma[tid] * rsqrtf(var + 1e-5f);
        sscale[tid] = sc;
        sshift[tid] = beta[tid] - mu * sc;
    }
    __syncthreads();
    int g = blockIdx.x;
    int c = tid & 31, r = tid >> 5;
    int beg = gptr[g], end = gptr[g + 1];
    float scl = sscale[c], shf = sshift[c];
    float s = 0.f, m = -INFINITY;
    for (int n = beg + r; n < end; n += 8) {
        float v = eluf(fmaf(bf2f(agg2[n * 32 + c]), scl, shf));
        s += v;
        m = fmaxf(m, v);
    }
    red[tid] = s;
    __syncthreads();
    int cnt = end - beg;
    if (r == 0) {
        float stot = 0.f;
#pragma unroll
        for (int i = 0; i < 8; ++i) stot += red[i * 32 + c];
        gr[c] = stot / fmaxf((float)cnt, 1.f);
    }
    __syncthreads();
    red[tid] = m;
    __syncthreads();
    if (r == 0) {
        float mtot = -INFINITY;
#pragma unroll
        for (int i = 0; i < 8; ++i) mtot = fmaxf(mtot, red[i * 32 + c]);
        gr[32 + c] = (cnt > 0) ? mtot : 0.f;
    }
    __syncthreads();
    if (tid < 32) {
        float acc = bm1[tid];
#pragma unroll
        for (int k = 0; k < 64; ++k) acc = fmaf(gr[k], Wm1[k * 32 + tid], acc);
        h[tid] = eluf(acc);
    }
    __syncthreads();
    if (tid < 2) {
        float acc = bm2[tid];
#pragma unroll
        for (int k = 0; k < 32; ++k) acc = fmaf(h[k], Wm2[k * 2 + tid], acc);
        out[g * 2 + tid] = acc;
    }
}

extern "C" void kernel_launch(void* const* d_in, const int* in_sizes, int n_in,
                              void* d_out, int out_size, void* d_ws, size_t ws_size,
                              hipStream_t stream) {
    const float* x    = (const float*)d_in[0];
    const int*   eidx = (const int*)d_in[1];
    const int*   src  = eidx;
    const int*   dst  = eidx + NE;
    const int*   batch = (const int*)d_in[3];
    const float* W1  = (const float*)d_in[4];
    const float* g1  = (const float*)d_in[6];
    const float* be1 = (const float*)d_in[7];
    const float* W2  = (const float*)d_in[8];
    const float* g2  = (const float*)d_in[10];
    const float* be2 = (const float*)d_in[11];
    const float* Wm1 = (const float*)d_in[12];
    const float* bm1 = (const float*)d_in[13];
    const float* Wm2 = (const float*)d_in[14];
    const float* bm2 = (const float*)d_in[15];
    float* out = (float*)d_out;

    // ---- workspace layout ----
    int*    bktCnt  = (int*)d_ws;                 // 800 (782 used) -- zeroed
    float*  S       = (float*)(bktCnt + 800);     // 512 stat floats -- zeroed
    int*    bktBase = (int*)(S + 512);            // 800 (783 used)
    int*    bktCur  = bktBase + 800;              // 800
    int*    gptr    = bktCur + 800;               // 544 (513 used)
    int*    ebuf    = gptr + 544;                 // NE packed {src<<7|dstLow}
    int*    csr     = ebuf + NE;                  // NE src ids
    int*    rowptr  = csr + NE;                   // 100032 (incl [NN])
    float*  dinv    = (float*)(rowptr + 100032);  // 100000
    bf16_t* y1      = (bf16_t*)(dinv + 100000);   // NN*64
    bf16_t* agg1    = y1 + NN * 64;               // NN*64
    bf16_t* y2      = agg1 + NN * 64;             // NN*32
    bf16_t* agg2    = y2 + NN * 32;               // NN*32

    float* sum1 = S;        float* sq1 = S + 64;
    float* sum2 = S + 128;  float* sq2 = S + 160;

    // ---- init: bucket counts + stats in one memset ----
    hipMemsetAsync(bktCnt, 0, (800 + 512) * sizeof(int), stream);

    // ---- CSR build: histogram -> scan(+gptr) -> LDS-agg scatter -> bucket sort ----
    k_hist<<<192, 256, 0, stream>>>(dst, bktCnt);
    k_small<<<2, 1024, 0, stream>>>(bktCnt, bktBase, bktCur, batch, gptr, rowptr);
    k_scatter_bkt<<<128, 256, 0, stream>>>(src, dst, bktCur, ebuf);
    k_bktsort<<<NBKT, 256, 0, stream>>>(bktBase, ebuf, csr, rowptr, dinv);

    // ---- layer 1 (bias dropped: BN shift-invariant; y1 = dinv * xW1) ----
    k_gemm1<<<(NN + 63) / 64, 256, 0, stream>>>(x, W1, dinv, y1);
    k_gather<64><<<2048, 256, 0, stream>>>(rowptr, csr, dinv, y1, agg1, sum1, sq1);

    // ---- layer 2 (BN+ELU+stats fused into GEMM; y2 = dinv * h1W2) ----
    k_bn_gemm2<<<(NN + 7) / 8, 256, 0, stream>>>(agg1, sum1, sq1, g1, be1, W2, dinv, y2);
    k_gather<32><<<2048, 256, 0, stream>>>(rowptr, csr, dinv, y2, agg2, sum2, sq2);

    // ---- pooling + MLP head in one kernel ----
    k_poolmlp<<<NG, 256, 0, stream>>>(agg2, sum2, sq2, g2, be2, gptr,
                                      Wm1, bm1, Wm2, bm2, out);
}